// Round 23
// baseline (33.969 us; speedup 1.0000x reference)
//
#include <hip/hip_runtime.h>

#define NB   4
#define CIN  32
#define HH   56
#define WW   56
#define GOUT 8
#define LOUT 8
#define KK   9
#define HW   (HH * WW)        // 3136
#define WSLICE 2304           // GOUT-slice floats per c (8*9*4*8)
#define WS_GU 148             // per-g LDS stride in uints (144+4) -> conflict-free b128
#define HP   58               // padded spatial dims
#define WP   58
#define THREADS 448           // one image row: 56 px * 8 g

typedef _Float16 h2v __attribute__((ext_vector_type(2)));

static __device__ __forceinline__ unsigned pack_h2(float a, float b) {
    h2v h = {(_Float16)a, (_Float16)b};
    return __builtin_bit_cast(unsigned, h);
}
static __device__ __forceinline__ h2v as_h2(unsigned u) {
    return __builtin_bit_cast(h2v, u);
}

// DPP xor-add over the 8-lane g-group: quad_perm(1,0,3,2)=0xB1 (lane^1),
// quad_perm(2,3,0,1)=0x4E (lane^2), row_half_mirror=0x141 (lane^7 within 8;
// valid for step 3 because quad-sums are already quad-uniform).
#define DPP_XADD(x, CTRL) \
    (x) += __int_as_float(__builtin_amdgcn_update_dpp( \
        0, __float_as_int(x), (CTRL), 0xF, 0xF, true))

// ---- pre-pass: x[n][ch][h][w] (f32) -> xt[n][hp][wp][ch] (f16, zero border) ----
__global__ __launch_bounds__(256) void transpose_x_kernel(
    const float* __restrict__ x, _Float16* __restrict__ xt)
{
    __shared__ float tile[CIN * 57];     // 57 stride: conflict-free transposed read
    const int b = blockIdx.x;            // n*HP + hp
    const int n = b / HP;
    const int hp = b - n * HP;
    const int h = hp - 1;
    const int tid = threadIdx.x;
    const bool rowok = (unsigned)h < (unsigned)HH;

    if (rowok) {
        for (int i = tid; i < CIN * WW; i += 256) {
            const int ch = i / WW;
            const int w  = i - ch * WW;  // lanes: w consecutive -> coalesced read
            tile[ch * 57 + w] = x[((n * CIN + ch) * HH + h) * WW + w];
        }
    }
    __syncthreads();
    _Float16* dst = xt + ((size_t)(n * HP + hp) * WP) * CIN;
    for (int i = tid; i < WP * CIN; i += 256) {
        const int wp = i >> 5;
        const int ch = i & 31;           // lanes: ch consecutive -> coalesced write
        const bool ok = rowok && (wp >= 1) && (wp <= WW);
        dst[i] = ok ? (_Float16)tile[ch * 57 + (wp - 1)] : (_Float16)0.0f;
    }
}

__global__ __launch_bounds__(THREADS, 2) void caps_routing_kernel(
    const _Float16* __restrict__ xt, const float* __restrict__ wt,
    float* __restrict__ out)
{
    // weights as fp16 (l0,l1)-pairs: ws[g][k*16 + lp*8 + m], per-g stride 148
    __shared__ __align__(16) unsigned ws[8 * WS_GU];   // 4736 B

    const int tid = threadIdx.x;
    const int c = blockIdx.y;
    const int rr = blockIdx.x;        // n*56 + h  (block-uniform -> SALU math)
    const int n = rr / HH;
    const int h = rr - n * HH;

    const int g = tid & 7;
    const int w = tid >> 3;           // 0..55

    // ---- x-gather: 9 b64 loads of 4 halves (2 l-pairs) each ----
    h2v xp[KK][2];
    const _Float16* base = xt + ((size_t)((n * HP + h) * WP + w)) * CIN + g * 4;
    #pragma unroll
    for (int ki = 0; ki < 3; ++ki)
        #pragma unroll
        for (int kj = 0; kj < 3; ++kj) {
            const uint2 u = *reinterpret_cast<const uint2*>(base + (ki * WP + kj) * CIN);
            xp[ki * 3 + kj][0] = as_h2(u.x);
            xp[ki * 3 + kj][1] = as_h2(u.y);
        }

    // ---- stage weights as fp16 l-pairs: 1152 uints over 448 threads ----
    {
        const float* wc = wt + c * WSLICE;
        for (int i = tid; i < 8 * 144; i += THREADS) {
            const int gg = i / 144;
            const int r  = i - gg * 144;          // r = k*16 + lp*8 + m
            const int k  = r >> 4;
            const int rp = r & 15;
            const int lp = rp >> 3;
            const int m  = rp & 7;
            const float* s = wc + gg * 288 + k * 32 + lp * 16 + m;
            ws[gg * WS_GU + r] = pack_h2(s[0], s[8]);   // (W[2lp][m], W[2lp+1][m])
        }
    }
    __syncthreads();

    // ---- priors via v_dot2_f32_f16: 2 MACs/slot, fp32 accumulate ----
    float pr[KK][8];
    float ks[8] = {0.f, 0.f, 0.f, 0.f, 0.f, 0.f, 0.f, 0.f};

    const unsigned* wg = &ws[g * WS_GU];
    #pragma unroll
    for (int k = 0; k < KK; ++k) {
        const uint4 ua = *reinterpret_cast<const uint4*>(wg + k * 16);      // lp0 m0..3
        const uint4 ub = *reinterpret_cast<const uint4*>(wg + k * 16 + 4);  // lp0 m4..7
        const uint4 uc = *reinterpret_cast<const uint4*>(wg + k * 16 + 8);  // lp1 m0..3
        const uint4 ud = *reinterpret_cast<const uint4*>(wg + k * 16 + 12); // lp1 m4..7
        const h2v x0 = xp[k][0], x1 = xp[k][1];
        float p0 = __builtin_amdgcn_fdot2(x0, as_h2(ua.x), 0.0f, false);
        float p1 = __builtin_amdgcn_fdot2(x0, as_h2(ua.y), 0.0f, false);
        float p2 = __builtin_amdgcn_fdot2(x0, as_h2(ua.z), 0.0f, false);
        float p3 = __builtin_amdgcn_fdot2(x0, as_h2(ua.w), 0.0f, false);
        float p4 = __builtin_amdgcn_fdot2(x0, as_h2(ub.x), 0.0f, false);
        float p5 = __builtin_amdgcn_fdot2(x0, as_h2(ub.y), 0.0f, false);
        float p6 = __builtin_amdgcn_fdot2(x0, as_h2(ub.z), 0.0f, false);
        float p7 = __builtin_amdgcn_fdot2(x0, as_h2(ub.w), 0.0f, false);
        p0 = __builtin_amdgcn_fdot2(x1, as_h2(uc.x), p0, false);
        p1 = __builtin_amdgcn_fdot2(x1, as_h2(uc.y), p1, false);
        p2 = __builtin_amdgcn_fdot2(x1, as_h2(uc.z), p2, false);
        p3 = __builtin_amdgcn_fdot2(x1, as_h2(uc.w), p3, false);
        p4 = __builtin_amdgcn_fdot2(x1, as_h2(ud.x), p4, false);
        p5 = __builtin_amdgcn_fdot2(x1, as_h2(ud.y), p5, false);
        p6 = __builtin_amdgcn_fdot2(x1, as_h2(ud.z), p6, false);
        p7 = __builtin_amdgcn_fdot2(x1, as_h2(ud.w), p7, false);
        pr[k][0] = p0; pr[k][1] = p1; pr[k][2] = p2; pr[k][3] = p3;
        pr[k][4] = p4; pr[k][5] = p5; pr[k][6] = p6; pr[k][7] = p7;
        ks[0] += p0; ks[1] += p1; ks[2] += p2; ks[3] += p3;
        ks[4] += p4; ks[5] += p5; ks[6] += p6; ks[7] += p7;
    }

    // ---- dynamic routing, ITERS = 3 (normalized probs — bounded) ----
    float logits[KK];
    #pragma unroll
    for (int k = 0; k < KK; ++k) logits[k] = 0.0f;

    float vv[8];
    #pragma unroll
    for (int it = 0; it < 3; ++it) {
        float s[8];
        float pre;   // scale applied to the reduced raw sum before squash
        if (it == 0) {
            #pragma unroll
            for (int m = 0; m < 8; ++m) s[m] = ks[m];
            pre = 1.0f / 9.0f;
        } else {
            float e[KK];
            float sum = 0.0f;
            #pragma unroll
            for (int k = 0; k < KK; ++k) { e[k] = __expf(logits[k]); sum += e[k]; }
            const float inv = __builtin_amdgcn_rcpf(sum);
            #pragma unroll
            for (int m = 0; m < 8; ++m) s[m] = 0.0f;
            #pragma unroll
            for (int k = 0; k < KK; ++k)
                #pragma unroll
                for (int m = 0; m < 8; ++m) s[m] = fmaf(e[k], pr[k][m], s[m]);
            #pragma unroll
            for (int m = 0; m < 8; ++m) s[m] *= inv;
            pre = 1.0f;
        }

        // g-group all-reduce via DPP (VALU-only, no LDS pipe)
        #pragma unroll
        for (int m = 0; m < 8; ++m) DPP_XADD(s[m], 0xB1);
        #pragma unroll
        for (int m = 0; m < 8; ++m) DPP_XADD(s[m], 0x4E);
        #pragma unroll
        for (int m = 0; m < 8; ++m) DPP_XADD(s[m], 0x141);

        // squash on s_true = pre*s: n2 = pre^2*|s|^2, v = (pre*f)*s
        float n2r = 0.0f;
        #pragma unroll
        for (int m = 0; m < 8; ++m) n2r = fmaf(s[m], s[m], n2r);
        const float n2 = n2r * (pre * pre);
        const float f = n2 * __builtin_amdgcn_rsqf(fmaxf(n2, 1e-30f))
                           * __builtin_amdgcn_rcpf(1.0f + n2);
        const float q = f * pre;
        #pragma unroll
        for (int m = 0; m < 8; ++m) vv[m] = q * s[m];

        if (it != 2) {
            #pragma unroll
            for (int k = 0; k < KK; ++k) {
                float d = 0.0f;
                #pragma unroll
                for (int m = 0; m < 8; ++m) d = fmaf(pr[k][m], vv[m], d);
                logits[k] += d;
            }
        }
    }

    // lane (w, g) writes output component m = g (static select chain)
    float outv = vv[0];
    #pragma unroll
    for (int m = 1; m < LOUT; ++m) if (g == m) outv = vv[m];
    out[(n * GOUT * LOUT + c * LOUT + g) * HW + h * WW + w] = outv;
}

extern "C" void kernel_launch(void* const* d_in, const int* in_sizes, int n_in,
                              void* d_out, int out_size, void* d_ws, size_t ws_size,
                              hipStream_t stream) {
    const float* x  = (const float*)d_in[0];
    const float* wt = (const float*)d_in[1];
    float* out = (float*)d_out;
    _Float16* xt = (_Float16*)d_ws;   // 4*58*58*32 halves = 861 KB scratch

    transpose_x_kernel<<<dim3(NB * HP), dim3(256), 0, stream>>>(x, xt);
    dim3 grid(NB * HH, GOUT);   // 224 x 8, 448 threads (one row x one c)
    caps_routing_kernel<<<grid, dim3(THREADS), 0, stream>>>(xt, wt, out);
}